// Round 8
// baseline (110.546 us; speedup 1.0000x reference)
//
#include <hip/hip_runtime.h>
#include <cstddef>

// Problem constants: N=2, H=W=64 (4x scale), S=17, P=8.

// ---------------------------------------------------------------------------
// Kernel 0: transpose W_in [32][1152] -> WT [1152][32]  (WT[(c*9+ij)*32+o])
__global__ void wtrans_kernel(const float* __restrict__ Wi, float* __restrict__ WT) {
    int t = blockIdx.x * 256 + threadIdx.x;   // 36864 total
    if (t >= 32 * 1152) return;
    int o = t / 1152, cc = t % 1152;
    WT[cc * 32 + o] = Wi[t];
}

// ---------------------------------------------------------------------------
// combo1: conv partials (blocks 0..1023) + chlast transposes (1024..8191).
__global__ __launch_bounds__(256)
void combo1_kernel(const float* __restrict__ KVt, const float* __restrict__ KV0,
                   const float* __restrict__ V01, const float* __restrict__ V02,
                   const float* __restrict__ WT,
                   float* __restrict__ part,
                   float* __restrict__ Xt4, float* __restrict__ Xt2,
                   float* __restrict__ Xt1) {
    __shared__ float smem[32 * 204];   // 26112 B (conv); chlast reuses prefix
    int bid = blockIdx.x;
    int tid = threadIdx.x;

    if (bid < 1024) {
        // ---------------- conv branch ----------------
        int kq = bid & 3;
        int h  = (bid >> 2) & 63;
        int img = bid >> 8;
        int w = tid & 63;
        int oh = __builtin_amdgcn_readfirstlane(tid >> 6);   // 0..3

        const float* X = ((img < 2) ? (KVt + (size_t)img * 128 * 4096)
                                    : (KV0 + (size_t)(img - 2) * 128 * 4096))
                         + (size_t)kq * 32 * 4096;

        for (int t = tid; t < 32 * 198; t += 256) {
            int c = t / 198;
            int rem = t - c * 198;
            int r = rem / 66, col = rem - r * 66;
            int hy = h + r - 1, wx = col - 1;
            float v = 0.f;
            if ((unsigned)hy < 64u && (unsigned)wx < 64u)
                v = X[(size_t)c * 4096 + hy * 64 + wx];
            smem[c * 204 + r * 68 + col] = v;
        }
        __syncthreads();

        const float* Wq = WT + (size_t)kq * 9216 + oh * 8;
        float acc[8];
        #pragma unroll
        for (int t = 0; t < 8; ++t) acc[t] = 0.f;

        for (int c = 0; c < 32; ++c) {
            const float* xr = smem + c * 204 + w;
            float xv[9];
            #pragma unroll
            for (int i = 0; i < 3; ++i)
                #pragma unroll
                for (int j = 0; j < 3; ++j)
                    xv[i * 3 + j] = xr[i * 68 + j];
            #pragma unroll
            for (int ij = 0; ij < 9; ++ij) {
                const float4* wp = (const float4*)(Wq + (c * 9 + ij) * 32);
                float4 w0 = wp[0], w1 = wp[1];
                float xs = xv[ij];
                acc[0] = fmaf(xs, w0.x, acc[0]); acc[1] = fmaf(xs, w0.y, acc[1]);
                acc[2] = fmaf(xs, w0.z, acc[2]); acc[3] = fmaf(xs, w0.w, acc[3]);
                acc[4] = fmaf(xs, w1.x, acc[4]); acc[5] = fmaf(xs, w1.y, acc[5]);
                acc[6] = fmaf(xs, w1.z, acc[6]); acc[7] = fmaf(xs, w1.w, acc[7]);
            }
        }

        int pix = h * 64 + w;
        float* pp = part + (((size_t)kq * 4 + img) * 32 + oh * 8) * 4096 + pix;
        #pragma unroll
        for (int t = 0; t < 8; ++t)
            pp[(size_t)t * 4096] = acc[t];
    } else {
        // ---------------- chlast branches ----------------
        float (*tile)[33] = (float(*)[33])smem;
        int tx = tid & 31, ty = tid >> 5;   // (32, 8)
        const float* Xn; float* Xtn;
        int s0, c0, C, S;
        if (bid < 2048) {            // KV04x -> Xt4  [C=128,S=4096]
            int b = bid - 1024;
            C = 128; S = 4096;
            s0 = (b & 127) * 32; c0 = ((b >> 7) & 3) * 32;
            int n = b >> 9;
            Xn = KV0 + (size_t)n * C * S;  Xtn = Xt4 + (size_t)n * S * C;
        } else if (bid < 4096) {     // V02x -> Xt2  [C=64,S=16384]
            int b = bid - 2048;
            C = 64; S = 16384;
            s0 = (b & 511) * 32; c0 = ((b >> 9) & 1) * 32;
            int n = b >> 10;
            Xn = V02 + (size_t)n * C * S;  Xtn = Xt2 + (size_t)n * S * C;
        } else {                     // V01x -> Xt1  [C=32,S=65536]
            int b = bid - 4096;
            C = 32; S = 65536;
            s0 = (b & 2047) * 32; c0 = 0;
            int n = b >> 11;
            Xn = V01 + (size_t)n * C * S;  Xtn = Xt1 + (size_t)n * S * C;
        }
        #pragma unroll
        for (int r = 0; r < 32; r += 8)
            tile[ty + r][tx] = Xn[(size_t)(c0 + ty + r) * S + s0 + tx];
        __syncthreads();
        #pragma unroll
        for (int r = 0; r < 32; r += 8)
            Xtn[(size_t)(s0 + ty + r) * C + c0 + tx] = tile[tx][ty + r];
    }
}

// ---------------------------------------------------------------------------
// Kernel 1b: sum 4 k-partials + l2norm -> AB[(img*4096+pix)*32+o]
__global__ __launch_bounds__(512)
void reduce_norm_kernel(const float* __restrict__ part, float* __restrict__ AB) {
    int tid = threadIdx.x;
    int o4 = tid & 7;
    int w  = tid >> 3;
    int img = blockIdx.x >> 6;
    int h   = blockIdx.x & 63;
    int pix = h * 64 + w;

    float a0 = 0.f, a1 = 0.f, a2 = 0.f, a3 = 0.f;
    #pragma unroll
    for (int kq = 0; kq < 4; ++kq) {
        const float* pp = part + (((size_t)kq * 4 + img) * 32 + o4 * 4) * 4096 + pix;
        a0 += pp[0];
        a1 += pp[4096];
        a2 += pp[2 * 4096];
        a3 += pp[3 * 4096];
    }
    float ss = a0 * a0 + a1 * a1 + a2 * a2 + a3 * a3;
    ss += __shfl_xor(ss, 1, 8);
    ss += __shfl_xor(ss, 2, 8);
    ss += __shfl_xor(ss, 4, 8);
    float inv = 1.f / fmaxf(sqrtf(ss), 1e-12f);
    float4 outv = make_float4(a0 * inv, a1 * inv, a2 * inv, a3 * inv);
    *((float4*)(AB + ((size_t)img * 4096 + pix) * 32) + o4) = outv;
}

// ---------------------------------------------------------------------------
// Legacy conv (tiny-ws fallback only).
#define CB 16
__global__ __launch_bounds__(512, 2)
void conv_l2_kernel(const float* __restrict__ KVt,
                    const float* __restrict__ KV0,
                    const float* __restrict__ WT,
                    float* __restrict__ AB) {
    __shared__ float Xh[CB * 3 * 66];
    __shared__ float Wl[CB * 9 * 32];
    int tid = threadIdx.x;
    int o4 = tid & 7;
    int w  = tid >> 3;
    int img = blockIdx.x >> 6;
    int h   = blockIdx.x & 63;
    const float* X = (img < 2) ? (KVt + (size_t)img * 128 * 4096)
                               : (KV0 + (size_t)(img - 2) * 128 * 4096);
    float acc0 = 0.f, acc1 = 0.f, acc2 = 0.f, acc3 = 0.f;
    for (int cc = 0; cc < 128 / CB; ++cc) {
        __syncthreads();
        for (int t = tid; t < CB * 3 * 66; t += 512) {
            int c2 = t / 198;
            int rem = t - c2 * 198;
            int r = rem / 66, col = rem - r * 66;
            int hy = h + r - 1, wx = col - 1;
            float v = 0.f;
            if ((unsigned)hy < 64u && (unsigned)wx < 64u)
                v = X[(size_t)(cc * CB + c2) * 4096 + hy * 64 + wx];
            Xh[t] = v;
        }
        for (int t = tid; t < CB * 9 * 32; t += 512)
            Wl[t] = WT[cc * (CB * 9 * 32) + t];
        __syncthreads();
        #pragma unroll 4
        for (int c2 = 0; c2 < CB; ++c2) {
            const float* xr = Xh + c2 * 198 + w;
            float xv[9];
            #pragma unroll
            for (int i = 0; i < 3; ++i)
                #pragma unroll
                for (int j = 0; j < 3; ++j)
                    xv[i * 3 + j] = xr[i * 66 + j];
            const float4* wp = (const float4*)(Wl + c2 * 9 * 32) + o4;
            #pragma unroll
            for (int ij = 0; ij < 9; ++ij) {
                float4 wv = wp[ij * 8];
                acc0 = fmaf(xv[ij], wv.x, acc0);
                acc1 = fmaf(xv[ij], wv.y, acc1);
                acc2 = fmaf(xv[ij], wv.z, acc2);
                acc3 = fmaf(xv[ij], wv.w, acc3);
            }
        }
    }
    float ss = acc0 * acc0 + acc1 * acc1 + acc2 * acc2 + acc3 * acc3;
    ss += __shfl_xor(ss, 1, 8);
    ss += __shfl_xor(ss, 2, 8);
    ss += __shfl_xor(ss, 4, 8);
    float inv = 1.f / fmaxf(sqrtf(ss), 1e-12f);
    int pix = h * 64 + w;
    float4 outv = make_float4(acc0 * inv, acc1 * inv, acc2 * inv, acc3 * inv);
    *((float4*)(AB + ((size_t)img * 4096 + pix) * 32) + o4) = outv;
}

// ---------------------------------------------------------------------------
// Kernel 2 v2: correlation with 8-lanes-per-displacement coalesced B reads.
__global__ __launch_bounds__(256)
void corr_flow_kernel(const float* __restrict__ A,
                      const float* __restrict__ B,
                      const float* __restrict__ subW,
                      float* __restrict__ maxOut,
                      float4* __restrict__ recs) {
    __shared__ float cosb[4][292];

    int tid = threadIdx.x;
    int wslot = tid >> 6;
    int lane = tid & 63;
    int q  = lane & 7;
    int dg = lane >> 3;
    int wid = (blockIdx.x * 256 + tid) >> 6;
    int n = wid >> 12, pix = wid & 4095;
    int h = pix >> 6, w = pix & 63;

    float4 af = *((const float4*)(A + ((size_t)n * 4096 + pix) * 32) + q);
    const float* Bn = B + (size_t)n * 4096 * 32;

    float bestV = -INFINITY; int bestD = 0x7fffffff;
    #pragma unroll 4
    for (int it = 0; it < 37; ++it) {
        int d = it * 8 + dg;
        if (d < 289) {
            int dv = d / 17 - 8, du = d % 17 - 8;
            int hy = h + dv, wx = w + du;
            float cv = 0.f;
            if ((unsigned)hy < 64u && (unsigned)wx < 64u) {
                float4 bv = *((const float4*)(Bn + ((size_t)hy * 64 + wx) * 32) + q);
                cv = af.x * bv.x + af.y * bv.y + af.z * bv.z + af.w * bv.w;
            }
            cv += __shfl_xor(cv, 1, 8);
            cv += __shfl_xor(cv, 2, 8);
            cv += __shfl_xor(cv, 4, 8);
            if (q == 0) cosb[wslot][d] = cv;
            if (cv > bestV) { bestV = cv; bestD = d; }
        }
    }
    #pragma unroll
    for (int m = 1; m < 64; m <<= 1) {
        float ov = __shfl_xor(bestV, m, 64);
        int   od = __shfl_xor(bestD, m, 64);
        if (ov > bestV || (ov == bestV && od < bestD)) { bestV = ov; bestD = od; }
    }
    __syncthreads();

    if (lane == 0) {
        int mi = bestD / 17, mj = bestD % 17;
        float hard[4] = {0.f, 0.f, 0.f, 0.f};
        #pragma unroll
        for (int p = 0; p < 3; ++p) {
            #pragma unroll
            for (int q3 = 0; q3 < 3; ++q3) {
                int ii = mi - 1 + p, jj = mj - 1 + q3;
                float l2v = 2.f;
                if ((unsigned)ii < 17u && (unsigned)jj < 17u)
                    l2v = 2.f - 2.f * cosb[wslot][ii * 17 + jj];
                #pragma unroll
                for (int o = 0; o < 4; ++o)
                    hard[o] = fmaf(subW[o * 9 + p * 3 + q3], l2v, hard[o]);
            }
        }
        float subU = fminf(fmaxf(-hard[2] / fmaxf(hard[0], 1e-6f), -1.f), 1.f);
        float subV = fminf(fmaxf(-hard[3] / fmaxf(hard[1], 1e-6f), -1.f), 1.f);
        float u = (float)(mj - 8) + subU;
        float v = (float)(mi - 8) + subV;
        maxOut[(size_t)n * 4096 + pix] = bestV;
        float xf = (float)w + u, yf = (float)h + v;
        float x0 = floorf(xf), y0 = floorf(yf);
        recs[(size_t)n * 4096 + pix] = make_float4(x0, y0, xf - x0, yf - x0 * 0.f - y0);
    }
}

// ---------------------------------------------------------------------------
// foldwarp body v3: 3-tap batched gathers (12 loads in flight).
template <int ST, int PAD, int HIN, int C>
__device__ __forceinline__
void foldwarp_body(int b, int tid, const float* __restrict__ Xt,
                   const float4* __restrict__ recs, float* __restrict__ out,
                   char* smem) {
    constexpr int HOUT = 64 * ST;
    constexpr int NC4 = C / 4;
    constexpr int XT = 256 / NC4;
    constexpr int XB = HOUT / XT;

    int4*   tO = (int4*)smem;                       // XT*9
    float4* tW = (float4*)(smem + XT * 9 * 16);     // XT*9
    float*  ob = (float*)(smem + XT * 9 * 32);      // XT*(C+1)

    int xblk = b % XB;
    int rest = b / XB;
    int y = rest % HOUT;
    int n = rest / HOUT;
    int c4 = tid % NC4;
    int lx = tid / NC4;

    int ry = (y + PAD) % ST;
    for (int e = tid; e < XT * 9; e += 256) {
        int ex = e / 9, tap = e - ex * 9;
        int ti = tap / 3, tj = tap - ti * 3;
        int xx = xblk * XT + ex;
        int i = ry + ti * ST;
        int ho = (y + PAD - i) / ST;
        int rxx = (xx + PAD) % ST;
        int j = rxx + tj * ST;
        int wo = (xx + PAD - j) / ST;
        int4 off = make_int4(0, 0, 0, 0);
        float4 wt = make_float4(0.f, 0.f, 0.f, 0.f);
        if ((unsigned)ho < 64u && (unsigned)wo < 64u) {
            float4 r = recs[n * 4096 + ho * 64 + wo];
            int x0 = (int)r.x, y0 = (int)r.y;
            float fx = r.z, fy = r.w;
            int offs[4]; float ws[4];
            #pragma unroll
            for (int k = 0; k < 4; ++k) {
                int dy = k >> 1, dx = k & 1;
                int yc = y0 + dy, xc = x0 + dx;
                int iy = i + yc * ST - PAD;
                int ix = j + xc * ST - PAD;
                bool v = ((unsigned)yc < 64u) && ((unsigned)xc < 64u) &&
                         ((unsigned)iy < (unsigned)HIN) && ((unsigned)ix < (unsigned)HIN);
                ws[k]   = v ? (dy ? r.w : 1.f - fy) * (dx ? fx : 1.f - fx) : 0.f;
                offs[k] = v ? (iy * HIN + ix) * C : 0;
            }
            off = make_int4(offs[0], offs[1], offs[2], offs[3]);
            wt  = make_float4(ws[0], ws[1], ws[2], ws[3]);
        }
        tO[e] = off;
        tW[e] = wt;
    }
    __syncthreads();

    const float* Xn = Xt + (size_t)n * HIN * HIN * C + c4 * 4;
    float a0 = 0.f, a1 = 0.f, a2 = 0.f, a3 = 0.f;
    #pragma unroll
    for (int g = 0; g < 3; ++g) {
        // read 3 tap records, issue 12 gathers back-to-back
        int4 o0 = tO[lx * 9 + g * 3 + 0];
        int4 o1 = tO[lx * 9 + g * 3 + 1];
        int4 o2 = tO[lx * 9 + g * 3 + 2];
        float4 v00 = *(const float4*)(Xn + o0.x);
        float4 v01 = *(const float4*)(Xn + o0.y);
        float4 v02 = *(const float4*)(Xn + o0.z);
        float4 v03 = *(const float4*)(Xn + o0.w);
        float4 v10 = *(const float4*)(Xn + o1.x);
        float4 v11 = *(const float4*)(Xn + o1.y);
        float4 v12 = *(const float4*)(Xn + o1.z);
        float4 v13 = *(const float4*)(Xn + o1.w);
        float4 v20 = *(const float4*)(Xn + o2.x);
        float4 v21 = *(const float4*)(Xn + o2.y);
        float4 v22 = *(const float4*)(Xn + o2.z);
        float4 v23 = *(const float4*)(Xn + o2.w);
        float4 w0 = tW[lx * 9 + g * 3 + 0];
        float4 w1 = tW[lx * 9 + g * 3 + 1];
        float4 w2 = tW[lx * 9 + g * 3 + 2];
        a0 = fmaf(w0.x, v00.x, a0); a1 = fmaf(w0.x, v00.y, a1);
        a2 = fmaf(w0.x, v00.z, a2); a3 = fmaf(w0.x, v00.w, a3);
        a0 = fmaf(w0.y, v01.x, a0); a1 = fmaf(w0.y, v01.y, a1);
        a2 = fmaf(w0.y, v01.z, a2); a3 = fmaf(w0.y, v01.w, a3);
        a0 = fmaf(w0.z, v02.x, a0); a1 = fmaf(w0.z, v02.y, a1);
        a2 = fmaf(w0.z, v02.z, a2); a3 = fmaf(w0.z, v02.w, a3);
        a0 = fmaf(w0.w, v03.x, a0); a1 = fmaf(w0.w, v03.y, a1);
        a2 = fmaf(w0.w, v03.z, a2); a3 = fmaf(w0.w, v03.w, a3);
        a0 = fmaf(w1.x, v10.x, a0); a1 = fmaf(w1.x, v10.y, a1);
        a2 = fmaf(w1.x, v10.z, a2); a3 = fmaf(w1.x, v10.w, a3);
        a0 = fmaf(w1.y, v11.x, a0); a1 = fmaf(w1.y, v11.y, a1);
        a2 = fmaf(w1.y, v11.z, a2); a3 = fmaf(w1.y, v11.w, a3);
        a0 = fmaf(w1.z, v12.x, a0); a1 = fmaf(w1.z, v12.y, a1);
        a2 = fmaf(w1.z, v12.z, a2); a3 = fmaf(w1.z, v12.w, a3);
        a0 = fmaf(w1.w, v13.x, a0); a1 = fmaf(w1.w, v13.y, a1);
        a2 = fmaf(w1.w, v13.z, a2); a3 = fmaf(w1.w, v13.w, a3);
        a0 = fmaf(w2.x, v20.x, a0); a1 = fmaf(w2.x, v20.y, a1);
        a2 = fmaf(w2.x, v20.z, a2); a3 = fmaf(w2.x, v20.w, a3);
        a0 = fmaf(w2.y, v21.x, a0); a1 = fmaf(w2.y, v21.y, a1);
        a2 = fmaf(w2.y, v21.z, a2); a3 = fmaf(w2.y, v21.w, a3);
        a0 = fmaf(w2.z, v22.x, a0); a1 = fmaf(w2.z, v22.y, a1);
        a2 = fmaf(w2.z, v22.z, a2); a3 = fmaf(w2.z, v22.w, a3);
        a0 = fmaf(w2.w, v23.x, a0); a1 = fmaf(w2.w, v23.y, a1);
        a2 = fmaf(w2.w, v23.z, a2); a3 = fmaf(w2.w, v23.w, a3);
    }
    const float s9 = 1.f / 9.f;
    ob[lx * (C + 1) + c4 * 4 + 0] = a0 * s9;
    ob[lx * (C + 1) + c4 * 4 + 1] = a1 * s9;
    ob[lx * (C + 1) + c4 * 4 + 2] = a2 * s9;
    ob[lx * (C + 1) + c4 * 4 + 3] = a3 * s9;
    __syncthreads();

    float* on = out + ((size_t)n * C * HOUT + y) * HOUT + xblk * XT;
    for (int e = tid; e < XT * C; e += 256) {
        int c = e / XT, xx = e - c * XT;
        on[(size_t)c * HOUT * HOUT + xx] = ob[xx * (C + 1) + c];
    }
}

// foldwarp_all: T1 [0,4096) | T4 [4096,5120) | T2 [5120,7168)
__global__ __launch_bounds__(256)
void foldwarp_all_kernel(const float* __restrict__ Xt4, const float* __restrict__ Xt2,
                         const float* __restrict__ Xt1, const float4* __restrict__ recs,
                         float* __restrict__ T4, float* __restrict__ T2,
                         float* __restrict__ T1) {
    __shared__ alignas(16) char smem[13440];
    int bid = blockIdx.x, tid = threadIdx.x;
    if (bid < 4096)       foldwarp_body<4, 4, 256, 32>(bid, tid, Xt1, recs, T1, smem);
    else if (bid < 5120)  foldwarp_body<1, 1, 64, 128>(bid - 4096, tid, Xt4, recs, T4, smem);
    else                  foldwarp_body<2, 2, 128, 64>(bid - 5120, tid, Xt2, recs, T2, smem);
}

// ---------------------------------------------------------------------------
// Kernel 3 v1 (fallback when ws is too small for transposed buffers).
template <int ST, int PAD, int HIN, int C>
__global__ void foldwarp_kernel(const float* __restrict__ X,
                                const float4* __restrict__ recs,
                                float* __restrict__ out) {
    constexpr int HOUT = 64 * ST;
    int t = blockIdx.x * 256 + threadIdx.x;
    int x = t % HOUT;
    int rest = t / HOUT;
    int y = rest % HOUT; rest /= HOUT;
    int c = rest % C;
    int n = rest / C;

    int ry = (y + PAD) % ST;
    int rx = (x + PAD) % ST;
    float acc = 0.f;
    #pragma unroll
    for (int ti = 0; ti < 3; ++ti) {
        int i = ry + ti * ST;
        int ho = (y + PAD - i) / ST;
        if ((unsigned)ho >= 64u) continue;
        #pragma unroll
        for (int tj = 0; tj < 3; ++tj) {
            int j = rx + tj * ST;
            int wo = (x + PAD - j) / ST;
            if ((unsigned)wo >= 64u) continue;
            float4 r = recs[n * 4096 + ho * 64 + wo];
            int x0 = (int)r.x, y0 = (int)r.y;
            float fx = r.z, fy = r.w;
            #pragma unroll
            for (int dy = 0; dy < 2; ++dy) {
                int yc = y0 + dy;
                if ((unsigned)yc >= 64u) continue;
                int iy = i + yc * ST - PAD;
                if ((unsigned)iy >= (unsigned)HIN) continue;
                float wgy = dy ? fy : (1.f - fy);
                #pragma unroll
                for (int dx = 0; dx < 2; ++dx) {
                    int xc = x0 + dx;
                    if ((unsigned)xc >= 64u) continue;
                    int ix = j + xc * ST - PAD;
                    if ((unsigned)ix >= (unsigned)HIN) continue;
                    float wgt = wgy * (dx ? fx : (1.f - fx));
                    acc = fmaf(X[(((size_t)n * C + c) * HIN + iy) * HIN + ix], wgt, acc);
                }
            }
        }
    }
    out[t] = acc * (1.f / 9.f);
}

// ---------------------------------------------------------------------------
extern "C" void kernel_launch(void* const* d_in, const int* in_sizes, int n_in,
                              void* d_out, int out_size, void* d_ws, size_t ws_size,
                              hipStream_t stream) {
    const float* KVt4x = (const float*)d_in[2];
    const float* V01x  = (const float*)d_in[3];
    const float* V02x  = (const float*)d_in[4];
    const float* KV04x = (const float*)d_in[5];
    const float* subA  = (const float*)d_in[6];
    const float* W_in  = (const float*)d_in[7];

    float* out = (float*)d_out;
    float* maxOut = out;
    float* T4 = out + 8192;
    float* T2 = T4 + 2 * 128 * 64 * 64;
    float* T1 = T2 + 2 * 64 * 128 * 128;

    float* ws = (float*)d_ws;
    float* WT = ws;                        // 36864
    float* AB = WT + 36864;                // 524288 (A = imgs 0-1, B = imgs 2-3)
    float* A  = AB;
    float* B  = AB + 262144;
    float4* recs = (float4*)(AB + 524288); // 8192 float4 = 32768 floats
    float* Xt4 = (float*)(recs + 8192);    // 2*4096*128  = 1048576
    float* Xt2 = Xt4 + 1048576;            // 2*16384*64  = 2097152
    float* Xt1 = Xt2 + 2097152;            // 2*65536*32  = 4194304
    float* part = Xt1 + 4194304;           // 4kq*4img*32*4096 = 2097152

    const size_t need_full = (36864ull + 524288 + 32768 +
                              1048576 + 2097152 + 4194304 + 2097152) * 4ull;
    const size_t need_min  = (36864ull + 524288 + 32768) * 4ull;

    hipLaunchKernelGGL(wtrans_kernel, dim3(144), dim3(256), 0, stream, W_in, WT);

    if (ws_size >= need_full) {
        hipLaunchKernelGGL(combo1_kernel, dim3(8192), dim3(256), 0, stream,
                           KVt4x, KV04x, V01x, V02x, WT, part, Xt4, Xt2, Xt1);
        hipLaunchKernelGGL(reduce_norm_kernel, dim3(256), dim3(512), 0, stream,
                           part, AB);
        hipLaunchKernelGGL(corr_flow_kernel, dim3(2048), dim3(256), 0, stream,
                           A, B, subA, maxOut, recs);
        hipLaunchKernelGGL(foldwarp_all_kernel, dim3(7168), dim3(256), 0, stream,
                           Xt4, Xt2, Xt1, recs, T4, T2, T1);
    } else if (ws_size >= need_min) {
        hipLaunchKernelGGL(conv_l2_kernel, dim3(256), dim3(512), 0, stream,
                           KVt4x, KV04x, WT, AB);
        hipLaunchKernelGGL(corr_flow_kernel, dim3(2048), dim3(256), 0, stream,
                           A, B, subA, maxOut, recs);
        hipLaunchKernelGGL((foldwarp_kernel<1, 1, 64, 128>),  dim3(4096),  dim3(256), 0, stream, KV04x, recs, T4);
        hipLaunchKernelGGL((foldwarp_kernel<2, 2, 128, 64>),  dim3(8192),  dim3(256), 0, stream, V02x, recs, T2);
        hipLaunchKernelGGL((foldwarp_kernel<4, 4, 256, 32>),  dim3(16384), dim3(256), 0, stream, V01x, recs, T1);
    }
}

// Round 9
// 109.479 us; speedup vs baseline: 1.0098x; 1.0098x over previous
//
#include <hip/hip_runtime.h>
#include <cstddef>

// Problem constants: N=2, H=W=64 (4x scale), S=17, P=8.

// ---------------------------------------------------------------------------
// Kernel 0: transpose W_in [32][1152] -> WT [1152][32]  (WT[(c*9+ij)*32+o])
__global__ void wtrans_kernel(const float* __restrict__ Wi, float* __restrict__ WT) {
    int t = blockIdx.x * 256 + threadIdx.x;   // 36864 total
    if (t >= 32 * 1152) return;
    int o = t / 1152, cc = t % 1152;
    WT[cc * 32 + o] = Wi[t];
}

// ---------------------------------------------------------------------------
// combo1: conv partials (blocks 0..1023) + chlast transposes (1024..8191).
__global__ __launch_bounds__(256)
void combo1_kernel(const float* __restrict__ KVt, const float* __restrict__ KV0,
                   const float* __restrict__ V01, const float* __restrict__ V02,
                   const float* __restrict__ WT,
                   float* __restrict__ part,
                   float* __restrict__ Xt4, float* __restrict__ Xt2,
                   float* __restrict__ Xt1) {
    __shared__ float smem[32 * 204];   // 26112 B (conv); chlast reuses prefix
    int bid = blockIdx.x;
    int tid = threadIdx.x;

    if (bid < 1024) {
        // ---------------- conv branch ----------------
        int kq = bid & 3;
        int h  = (bid >> 2) & 63;
        int img = bid >> 8;
        int w = tid & 63;
        int oh = __builtin_amdgcn_readfirstlane(tid >> 6);   // 0..3

        const float* X = ((img < 2) ? (KVt + (size_t)img * 128 * 4096)
                                    : (KV0 + (size_t)(img - 2) * 128 * 4096))
                         + (size_t)kq * 32 * 4096;

        for (int t = tid; t < 32 * 198; t += 256) {
            int c = t / 198;
            int rem = t - c * 198;
            int r = rem / 66, col = rem - r * 66;
            int hy = h + r - 1, wx = col - 1;
            float v = 0.f;
            if ((unsigned)hy < 64u && (unsigned)wx < 64u)
                v = X[(size_t)c * 4096 + hy * 64 + wx];
            smem[c * 204 + r * 68 + col] = v;
        }
        __syncthreads();

        const float* Wq = WT + (size_t)kq * 9216 + oh * 8;
        float acc[8];
        #pragma unroll
        for (int t = 0; t < 8; ++t) acc[t] = 0.f;

        for (int c = 0; c < 32; ++c) {
            const float* xr = smem + c * 204 + w;
            float xv[9];
            #pragma unroll
            for (int i = 0; i < 3; ++i)
                #pragma unroll
                for (int j = 0; j < 3; ++j)
                    xv[i * 3 + j] = xr[i * 68 + j];
            #pragma unroll
            for (int ij = 0; ij < 9; ++ij) {
                const float4* wp = (const float4*)(Wq + (c * 9 + ij) * 32);
                float4 w0 = wp[0], w1 = wp[1];
                float xs = xv[ij];
                acc[0] = fmaf(xs, w0.x, acc[0]); acc[1] = fmaf(xs, w0.y, acc[1]);
                acc[2] = fmaf(xs, w0.z, acc[2]); acc[3] = fmaf(xs, w0.w, acc[3]);
                acc[4] = fmaf(xs, w1.x, acc[4]); acc[5] = fmaf(xs, w1.y, acc[5]);
                acc[6] = fmaf(xs, w1.z, acc[6]); acc[7] = fmaf(xs, w1.w, acc[7]);
            }
        }

        int pix = h * 64 + w;
        float* pp = part + (((size_t)kq * 4 + img) * 32 + oh * 8) * 4096 + pix;
        #pragma unroll
        for (int t = 0; t < 8; ++t)
            pp[(size_t)t * 4096] = acc[t];
    } else {
        // ---------------- chlast branches ----------------
        float (*tile)[33] = (float(*)[33])smem;
        int tx = tid & 31, ty = tid >> 5;   // (32, 8)
        const float* Xn; float* Xtn;
        int s0, c0, C, S;
        if (bid < 2048) {            // KV04x -> Xt4  [C=128,S=4096]
            int b = bid - 1024;
            C = 128; S = 4096;
            s0 = (b & 127) * 32; c0 = ((b >> 7) & 3) * 32;
            int n = b >> 9;
            Xn = KV0 + (size_t)n * C * S;  Xtn = Xt4 + (size_t)n * S * C;
        } else if (bid < 4096) {     // V02x -> Xt2  [C=64,S=16384]
            int b = bid - 2048;
            C = 64; S = 16384;
            s0 = (b & 511) * 32; c0 = ((b >> 9) & 1) * 32;
            int n = b >> 10;
            Xn = V02 + (size_t)n * C * S;  Xtn = Xt2 + (size_t)n * S * C;
        } else {                     // V01x -> Xt1  [C=32,S=65536]
            int b = bid - 4096;
            C = 32; S = 65536;
            s0 = (b & 2047) * 32; c0 = 0;
            int n = b >> 11;
            Xn = V01 + (size_t)n * C * S;  Xtn = Xt1 + (size_t)n * S * C;
        }
        #pragma unroll
        for (int r = 0; r < 32; r += 8)
            tile[ty + r][tx] = Xn[(size_t)(c0 + ty + r) * S + s0 + tx];
        __syncthreads();
        #pragma unroll
        for (int r = 0; r < 32; r += 8)
            Xtn[(size_t)(s0 + ty + r) * C + c0 + tx] = tile[tx][ty + r];
    }
}

// ---------------------------------------------------------------------------
// Kernel 1b: sum 4 k-partials + l2norm -> AB[(img*4096+pix)*32+o]
__global__ __launch_bounds__(512)
void reduce_norm_kernel(const float* __restrict__ part, float* __restrict__ AB) {
    int tid = threadIdx.x;
    int o4 = tid & 7;
    int w  = tid >> 3;
    int img = blockIdx.x >> 6;
    int h   = blockIdx.x & 63;
    int pix = h * 64 + w;

    float a0 = 0.f, a1 = 0.f, a2 = 0.f, a3 = 0.f;
    #pragma unroll
    for (int kq = 0; kq < 4; ++kq) {
        const float* pp = part + (((size_t)kq * 4 + img) * 32 + o4 * 4) * 4096 + pix;
        a0 += pp[0];
        a1 += pp[4096];
        a2 += pp[2 * 4096];
        a3 += pp[3 * 4096];
    }
    float ss = a0 * a0 + a1 * a1 + a2 * a2 + a3 * a3;
    ss += __shfl_xor(ss, 1, 8);
    ss += __shfl_xor(ss, 2, 8);
    ss += __shfl_xor(ss, 4, 8);
    float inv = 1.f / fmaxf(sqrtf(ss), 1e-12f);
    float4 outv = make_float4(a0 * inv, a1 * inv, a2 * inv, a3 * inv);
    *((float4*)(AB + ((size_t)img * 4096 + pix) * 32) + o4) = outv;
}

// ---------------------------------------------------------------------------
// Legacy conv (tiny-ws fallback only).
#define CB 16
__global__ __launch_bounds__(512, 2)
void conv_l2_kernel(const float* __restrict__ KVt,
                    const float* __restrict__ KV0,
                    const float* __restrict__ WT,
                    float* __restrict__ AB) {
    __shared__ float Xh[CB * 3 * 66];
    __shared__ float Wl[CB * 9 * 32];
    int tid = threadIdx.x;
    int o4 = tid & 7;
    int w  = tid >> 3;
    int img = blockIdx.x >> 6;
    int h   = blockIdx.x & 63;
    const float* X = (img < 2) ? (KVt + (size_t)img * 128 * 4096)
                               : (KV0 + (size_t)(img - 2) * 128 * 4096);
    float acc0 = 0.f, acc1 = 0.f, acc2 = 0.f, acc3 = 0.f;
    for (int cc = 0; cc < 128 / CB; ++cc) {
        __syncthreads();
        for (int t = tid; t < CB * 3 * 66; t += 512) {
            int c2 = t / 198;
            int rem = t - c2 * 198;
            int r = rem / 66, col = rem - r * 66;
            int hy = h + r - 1, wx = col - 1;
            float v = 0.f;
            if ((unsigned)hy < 64u && (unsigned)wx < 64u)
                v = X[(size_t)(cc * CB + c2) * 4096 + hy * 64 + wx];
            Xh[t] = v;
        }
        for (int t = tid; t < CB * 9 * 32; t += 512)
            Wl[t] = WT[cc * (CB * 9 * 32) + t];
        __syncthreads();
        #pragma unroll 4
        for (int c2 = 0; c2 < CB; ++c2) {
            const float* xr = Xh + c2 * 198 + w;
            float xv[9];
            #pragma unroll
            for (int i = 0; i < 3; ++i)
                #pragma unroll
                for (int j = 0; j < 3; ++j)
                    xv[i * 3 + j] = xr[i * 66 + j];
            const float4* wp = (const float4*)(Wl + c2 * 9 * 32) + o4;
            #pragma unroll
            for (int ij = 0; ij < 9; ++ij) {
                float4 wv = wp[ij * 8];
                acc0 = fmaf(xv[ij], wv.x, acc0);
                acc1 = fmaf(xv[ij], wv.y, acc1);
                acc2 = fmaf(xv[ij], wv.z, acc2);
                acc3 = fmaf(xv[ij], wv.w, acc3);
            }
        }
    }
    float ss = acc0 * acc0 + acc1 * acc1 + acc2 * acc2 + acc3 * acc3;
    ss += __shfl_xor(ss, 1, 8);
    ss += __shfl_xor(ss, 2, 8);
    ss += __shfl_xor(ss, 4, 8);
    float inv = 1.f / fmaxf(sqrtf(ss), 1e-12f);
    int pix = h * 64 + w;
    float4 outv = make_float4(acc0 * inv, acc1 * inv, acc2 * inv, acc3 * inv);
    *((float4*)(AB + ((size_t)img * 4096 + pix) * 32) + o4) = outv;
}

// ---------------------------------------------------------------------------
// Kernel 2 v2: correlation with 8-lanes-per-displacement coalesced B reads.
__global__ __launch_bounds__(256)
void corr_flow_kernel(const float* __restrict__ A,
                      const float* __restrict__ B,
                      const float* __restrict__ subW,
                      float* __restrict__ maxOut,
                      float4* __restrict__ recs) {
    __shared__ float cosb[4][292];

    int tid = threadIdx.x;
    int wslot = tid >> 6;
    int lane = tid & 63;
    int q  = lane & 7;
    int dg = lane >> 3;
    int wid = (blockIdx.x * 256 + tid) >> 6;
    int n = wid >> 12, pix = wid & 4095;
    int h = pix >> 6, w = pix & 63;

    float4 af = *((const float4*)(A + ((size_t)n * 4096 + pix) * 32) + q);
    const float* Bn = B + (size_t)n * 4096 * 32;

    float bestV = -INFINITY; int bestD = 0x7fffffff;
    #pragma unroll 4
    for (int it = 0; it < 37; ++it) {
        int d = it * 8 + dg;
        if (d < 289) {
            int dv = d / 17 - 8, du = d % 17 - 8;
            int hy = h + dv, wx = w + du;
            float cv = 0.f;
            if ((unsigned)hy < 64u && (unsigned)wx < 64u) {
                float4 bv = *((const float4*)(Bn + ((size_t)hy * 64 + wx) * 32) + q);
                cv = af.x * bv.x + af.y * bv.y + af.z * bv.z + af.w * bv.w;
            }
            cv += __shfl_xor(cv, 1, 8);
            cv += __shfl_xor(cv, 2, 8);
            cv += __shfl_xor(cv, 4, 8);
            if (q == 0) cosb[wslot][d] = cv;
            if (cv > bestV) { bestV = cv; bestD = d; }
        }
    }
    #pragma unroll
    for (int m = 1; m < 64; m <<= 1) {
        float ov = __shfl_xor(bestV, m, 64);
        int   od = __shfl_xor(bestD, m, 64);
        if (ov > bestV || (ov == bestV && od < bestD)) { bestV = ov; bestD = od; }
    }
    __syncthreads();

    if (lane == 0) {
        int mi = bestD / 17, mj = bestD % 17;
        float hard[4] = {0.f, 0.f, 0.f, 0.f};
        #pragma unroll
        for (int p = 0; p < 3; ++p) {
            #pragma unroll
            for (int q3 = 0; q3 < 3; ++q3) {
                int ii = mi - 1 + p, jj = mj - 1 + q3;
                float l2v = 2.f;
                if ((unsigned)ii < 17u && (unsigned)jj < 17u)
                    l2v = 2.f - 2.f * cosb[wslot][ii * 17 + jj];
                #pragma unroll
                for (int o = 0; o < 4; ++o)
                    hard[o] = fmaf(subW[o * 9 + p * 3 + q3], l2v, hard[o]);
            }
        }
        float subU = fminf(fmaxf(-hard[2] / fmaxf(hard[0], 1e-6f), -1.f), 1.f);
        float subV = fminf(fmaxf(-hard[3] / fmaxf(hard[1], 1e-6f), -1.f), 1.f);
        float u = (float)(mj - 8) + subU;
        float v = (float)(mi - 8) + subV;
        maxOut[(size_t)n * 4096 + pix] = bestV;
        float xf = (float)w + u, yf = (float)h + v;
        float x0 = floorf(xf), y0 = floorf(yf);
        recs[(size_t)n * 4096 + pix] = make_float4(x0, y0, xf - x0, yf - y0);
    }
}

// ---------------------------------------------------------------------------
// foldwarp body: 3-tap batched gathers.
template <int ST, int PAD, int HIN, int C>
__device__ __forceinline__
void foldwarp_body(int b, int tid, const float* __restrict__ Xt,
                   const float4* __restrict__ recs, float* __restrict__ out,
                   char* smem) {
    constexpr int HOUT = 64 * ST;
    constexpr int NC4 = C / 4;
    constexpr int XT = 256 / NC4;
    constexpr int XB = HOUT / XT;

    int4*   tO = (int4*)smem;                       // XT*9
    float4* tW = (float4*)(smem + XT * 9 * 16);     // XT*9
    float*  ob = (float*)(smem + XT * 9 * 32);      // XT*(C+1)

    int xblk = b % XB;
    int rest = b / XB;
    int y = rest % HOUT;
    int n = rest / HOUT;
    int c4 = tid % NC4;
    int lx = tid / NC4;

    int ry = (y + PAD) % ST;
    for (int e = tid; e < XT * 9; e += 256) {
        int ex = e / 9, tap = e - ex * 9;
        int ti = tap / 3, tj = tap - ti * 3;
        int xx = xblk * XT + ex;
        int i = ry + ti * ST;
        int ho = (y + PAD - i) / ST;
        int rxx = (xx + PAD) % ST;
        int j = rxx + tj * ST;
        int wo = (xx + PAD - j) / ST;
        int4 off = make_int4(0, 0, 0, 0);
        float4 wt = make_float4(0.f, 0.f, 0.f, 0.f);
        if ((unsigned)ho < 64u && (unsigned)wo < 64u) {
            float4 r = recs[n * 4096 + ho * 64 + wo];
            int x0 = (int)r.x, y0 = (int)r.y;
            float fx = r.z, fy = r.w;
            int offs[4]; float ws[4];
            #pragma unroll
            for (int k = 0; k < 4; ++k) {
                int dy = k >> 1, dx = k & 1;
                int yc = y0 + dy, xc = x0 + dx;
                int iy = i + yc * ST - PAD;
                int ix = j + xc * ST - PAD;
                bool v = ((unsigned)yc < 64u) && ((unsigned)xc < 64u) &&
                         ((unsigned)iy < (unsigned)HIN) && ((unsigned)ix < (unsigned)HIN);
                ws[k]   = v ? (dy ? r.w : 1.f - fy) * (dx ? fx : 1.f - fx) : 0.f;
                offs[k] = v ? (iy * HIN + ix) * C : 0;
            }
            off = make_int4(offs[0], offs[1], offs[2], offs[3]);
            wt  = make_float4(ws[0], ws[1], ws[2], ws[3]);
        }
        tO[e] = off;
        tW[e] = wt;
    }
    __syncthreads();

    const float* Xn = Xt + (size_t)n * HIN * HIN * C + c4 * 4;
    float a0 = 0.f, a1 = 0.f, a2 = 0.f, a3 = 0.f;
    #pragma unroll
    for (int g = 0; g < 3; ++g) {
        int4 o0 = tO[lx * 9 + g * 3 + 0];
        int4 o1 = tO[lx * 9 + g * 3 + 1];
        int4 o2 = tO[lx * 9 + g * 3 + 2];
        float4 v00 = *(const float4*)(Xn + o0.x);
        float4 v01 = *(const float4*)(Xn + o0.y);
        float4 v02 = *(const float4*)(Xn + o0.z);
        float4 v03 = *(const float4*)(Xn + o0.w);
        float4 v10 = *(const float4*)(Xn + o1.x);
        float4 v11 = *(const float4*)(Xn + o1.y);
        float4 v12 = *(const float4*)(Xn + o1.z);
        float4 v13 = *(const float4*)(Xn + o1.w);
        float4 v20 = *(const float4*)(Xn + o2.x);
        float4 v21 = *(const float4*)(Xn + o2.y);
        float4 v22 = *(const float4*)(Xn + o2.z);
        float4 v23 = *(const float4*)(Xn + o2.w);
        float4 w0 = tW[lx * 9 + g * 3 + 0];
        float4 w1 = tW[lx * 9 + g * 3 + 1];
        float4 w2 = tW[lx * 9 + g * 3 + 2];
        a0 = fmaf(w0.x, v00.x, a0); a1 = fmaf(w0.x, v00.y, a1);
        a2 = fmaf(w0.x, v00.z, a2); a3 = fmaf(w0.x, v00.w, a3);
        a0 = fmaf(w0.y, v01.x, a0); a1 = fmaf(w0.y, v01.y, a1);
        a2 = fmaf(w0.y, v01.z, a2); a3 = fmaf(w0.y, v01.w, a3);
        a0 = fmaf(w0.z, v02.x, a0); a1 = fmaf(w0.z, v02.y, a1);
        a2 = fmaf(w0.z, v02.z, a2); a3 = fmaf(w0.z, v02.w, a3);
        a0 = fmaf(w0.w, v03.x, a0); a1 = fmaf(w0.w, v03.y, a1);
        a2 = fmaf(w0.w, v03.z, a2); a3 = fmaf(w0.w, v03.w, a3);
        a0 = fmaf(w1.x, v10.x, a0); a1 = fmaf(w1.x, v10.y, a1);
        a2 = fmaf(w1.x, v10.z, a2); a3 = fmaf(w1.x, v10.w, a3);
        a0 = fmaf(w1.y, v11.x, a0); a1 = fmaf(w1.y, v11.y, a1);
        a2 = fmaf(w1.y, v11.z, a2); a3 = fmaf(w1.y, v11.w, a3);
        a0 = fmaf(w1.z, v12.x, a0); a1 = fmaf(w1.z, v12.y, a1);
        a2 = fmaf(w1.z, v12.z, a2); a3 = fmaf(w1.z, v12.w, a3);
        a0 = fmaf(w1.w, v13.x, a0); a1 = fmaf(w1.w, v13.y, a1);
        a2 = fmaf(w1.w, v13.z, a2); a3 = fmaf(w1.w, v13.w, a3);
        a0 = fmaf(w2.x, v20.x, a0); a1 = fmaf(w2.x, v20.y, a1);
        a2 = fmaf(w2.x, v20.z, a2); a3 = fmaf(w2.x, v20.w, a3);
        a0 = fmaf(w2.y, v21.x, a0); a1 = fmaf(w2.y, v21.y, a1);
        a2 = fmaf(w2.y, v21.z, a2); a3 = fmaf(w2.y, v21.w, a3);
        a0 = fmaf(w2.z, v22.x, a0); a1 = fmaf(w2.z, v22.y, a1);
        a2 = fmaf(w2.z, v22.z, a2); a3 = fmaf(w2.z, v22.w, a3);
        a0 = fmaf(w2.w, v23.x, a0); a1 = fmaf(w2.w, v23.y, a1);
        a2 = fmaf(w2.w, v23.z, a2); a3 = fmaf(w2.w, v23.w, a3);
    }
    const float s9 = 1.f / 9.f;
    ob[lx * (C + 1) + c4 * 4 + 0] = a0 * s9;
    ob[lx * (C + 1) + c4 * 4 + 1] = a1 * s9;
    ob[lx * (C + 1) + c4 * 4 + 2] = a2 * s9;
    ob[lx * (C + 1) + c4 * 4 + 3] = a3 * s9;
    __syncthreads();

    float* on = out + ((size_t)n * C * HOUT + y) * HOUT + xblk * XT;
    for (int e = tid; e < XT * C; e += 256) {
        int c = e / XT, xx = e - c * XT;
        on[(size_t)c * HOUT * HOUT + xx] = ob[xx * (C + 1) + c];
    }
}

// foldwarp_all with XCD banding: xcd = bid&7 (HW round-robins blocks to XCDs),
// slot = bid>>3. Per XCD: 512 contiguous T1 blocks (64-row y-band, ~4.6MB
// footprint ~ its private 4MB L2), 128 T4, 256 T2 — bands stay L2-hot.
__global__ __launch_bounds__(256)
void foldwarp_all_kernel(const float* __restrict__ Xt4, const float* __restrict__ Xt2,
                         const float* __restrict__ Xt1, const float4* __restrict__ recs,
                         float* __restrict__ T4, float* __restrict__ T2,
                         float* __restrict__ T1) {
    __shared__ alignas(16) char smem[13440];
    int bid = blockIdx.x, tid = threadIdx.x;
    int xcd  = bid & 7;
    int slot = bid >> 3;          // 0..895 per XCD
    if (slot < 512)
        foldwarp_body<4, 4, 256, 32>(xcd * 512 + slot, tid, Xt1, recs, T1, smem);
    else if (slot < 640)
        foldwarp_body<1, 1, 64, 128>(xcd * 128 + (slot - 512), tid, Xt4, recs, T4, smem);
    else
        foldwarp_body<2, 2, 128, 64>(xcd * 256 + (slot - 640), tid, Xt2, recs, T2, smem);
}

// ---------------------------------------------------------------------------
// Kernel 3 v1 (fallback when ws is too small for transposed buffers).
template <int ST, int PAD, int HIN, int C>
__global__ void foldwarp_kernel(const float* __restrict__ X,
                                const float4* __restrict__ recs,
                                float* __restrict__ out) {
    constexpr int HOUT = 64 * ST;
    int t = blockIdx.x * 256 + threadIdx.x;
    int x = t % HOUT;
    int rest = t / HOUT;
    int y = rest % HOUT; rest /= HOUT;
    int c = rest % C;
    int n = rest / C;

    int ry = (y + PAD) % ST;
    int rx = (x + PAD) % ST;
    float acc = 0.f;
    #pragma unroll
    for (int ti = 0; ti < 3; ++ti) {
        int i = ry + ti * ST;
        int ho = (y + PAD - i) / ST;
        if ((unsigned)ho >= 64u) continue;
        #pragma unroll
        for (int tj = 0; tj < 3; ++tj) {
            int j = rx + tj * ST;
            int wo = (x + PAD - j) / ST;
            if ((unsigned)wo >= 64u) continue;
            float4 r = recs[n * 4096 + ho * 64 + wo];
            int x0 = (int)r.x, y0 = (int)r.y;
            float fx = r.z, fy = r.w;
            #pragma unroll
            for (int dy = 0; dy < 2; ++dy) {
                int yc = y0 + dy;
                if ((unsigned)yc >= 64u) continue;
                int iy = i + yc * ST - PAD;
                if ((unsigned)iy >= (unsigned)HIN) continue;
                float wgy = dy ? fy : (1.f - fy);
                #pragma unroll
                for (int dx = 0; dx < 2; ++dx) {
                    int xc = x0 + dx;
                    if ((unsigned)xc >= 64u) continue;
                    int ix = j + xc * ST - PAD;
                    if ((unsigned)ix >= (unsigned)HIN) continue;
                    float wgt = wgy * (dx ? fx : (1.f - fx));
                    acc = fmaf(X[(((size_t)n * C + c) * HIN + iy) * HIN + ix], wgt, acc);
                }
            }
        }
    }
    out[t] = acc * (1.f / 9.f);
}

// ---------------------------------------------------------------------------
extern "C" void kernel_launch(void* const* d_in, const int* in_sizes, int n_in,
                              void* d_out, int out_size, void* d_ws, size_t ws_size,
                              hipStream_t stream) {
    const float* KVt4x = (const float*)d_in[2];
    const float* V01x  = (const float*)d_in[3];
    const float* V02x  = (const float*)d_in[4];
    const float* KV04x = (const float*)d_in[5];
    const float* subA  = (const float*)d_in[6];
    const float* W_in  = (const float*)d_in[7];

    float* out = (float*)d_out;
    float* maxOut = out;
    float* T4 = out + 8192;
    float* T2 = T4 + 2 * 128 * 64 * 64;
    float* T1 = T2 + 2 * 64 * 128 * 128;

    float* ws = (float*)d_ws;
    float* WT = ws;                        // 36864
    float* AB = WT + 36864;                // 524288 (A = imgs 0-1, B = imgs 2-3)
    float* A  = AB;
    float* B  = AB + 262144;
    float4* recs = (float4*)(AB + 524288); // 8192 float4 = 32768 floats
    float* Xt4 = (float*)(recs + 8192);    // 2*4096*128  = 1048576
    float* Xt2 = Xt4 + 1048576;            // 2*16384*64  = 2097152
    float* Xt1 = Xt2 + 2097152;            // 2*65536*32  = 4194304
    float* part = Xt1 + 4194304;           // 4kq*4img*32*4096 = 2097152

    const size_t need_full = (36864ull + 524288 + 32768 +
                              1048576 + 2097152 + 4194304 + 2097152) * 4ull;
    const size_t need_min  = (36864ull + 524288 + 32768) * 4ull;

    hipLaunchKernelGGL(wtrans_kernel, dim3(144), dim3(256), 0, stream, W_in, WT);

    if (ws_size >= need_full) {
        hipLaunchKernelGGL(combo1_kernel, dim3(8192), dim3(256), 0, stream,
                           KVt4x, KV04x, V01x, V02x, WT, part, Xt4, Xt2, Xt1);
        hipLaunchKernelGGL(reduce_norm_kernel, dim3(256), dim3(512), 0, stream,
                           part, AB);
        hipLaunchKernelGGL(corr_flow_kernel, dim3(2048), dim3(256), 0, stream,
                           A, B, subA, maxOut, recs);
        hipLaunchKernelGGL(foldwarp_all_kernel, dim3(7168), dim3(256), 0, stream,
                           Xt4, Xt2, Xt1, recs, T4, T2, T1);
    } else if (ws_size >= need_min) {
        hipLaunchKernelGGL(conv_l2_kernel, dim3(256), dim3(512), 0, stream,
                           KVt4x, KV04x, WT, AB);
        hipLaunchKernelGGL(corr_flow_kernel, dim3(2048), dim3(256), 0, stream,
                           A, B, subA, maxOut, recs);
        hipLaunchKernelGGL((foldwarp_kernel<1, 1, 64, 128>),  dim3(4096),  dim3(256), 0, stream, KV04x, recs, T4);
        hipLaunchKernelGGL((foldwarp_kernel<2, 2, 128, 64>),  dim3(8192),  dim3(256), 0, stream, V02x, recs, T2);
        hipLaunchKernelGGL((foldwarp_kernel<4, 4, 256, 32>),  dim3(16384), dim3(256), 0, stream, V01x, recs, T1);
    }
}

// Round 10
// 102.429 us; speedup vs baseline: 1.0792x; 1.0688x over previous
//
#include <hip/hip_runtime.h>
#include <cstddef>

// Problem constants: N=2, H=W=64 (4x scale), S=17, P=8.

// ---------------------------------------------------------------------------
// Kernel 0: transpose W_in [32][1152] -> WT [1152][32]  (WT[(c*9+ij)*32+o])
__global__ void wtrans_kernel(const float* __restrict__ Wi, float* __restrict__ WT) {
    int t = blockIdx.x * 256 + threadIdx.x;   // 36864 total
    if (t >= 32 * 1152) return;
    int o = t / 1152, cc = t % 1152;
    WT[cc * 32 + o] = Wi[t];
}

// ---------------------------------------------------------------------------
// combo1: conv partials (blocks 0..1023) + chlast transposes (1024..8191).
__global__ __launch_bounds__(256)
void combo1_kernel(const float* __restrict__ KVt, const float* __restrict__ KV0,
                   const float* __restrict__ V01, const float* __restrict__ V02,
                   const float* __restrict__ WT,
                   float* __restrict__ part,
                   float* __restrict__ Xt4, float* __restrict__ Xt2,
                   float* __restrict__ Xt1) {
    __shared__ float smem[32 * 204];   // 26112 B (conv); chlast reuses prefix
    int bid = blockIdx.x;
    int tid = threadIdx.x;

    if (bid < 1024) {
        // ---------------- conv branch ----------------
        int kq = bid & 3;
        int h  = (bid >> 2) & 63;
        int img = bid >> 8;
        int w = tid & 63;
        int oh = __builtin_amdgcn_readfirstlane(tid >> 6);   // 0..3

        const float* X = ((img < 2) ? (KVt + (size_t)img * 128 * 4096)
                                    : (KV0 + (size_t)(img - 2) * 128 * 4096))
                         + (size_t)kq * 32 * 4096;

        for (int t = tid; t < 32 * 198; t += 256) {
            int c = t / 198;
            int rem = t - c * 198;
            int r = rem / 66, col = rem - r * 66;
            int hy = h + r - 1, wx = col - 1;
            float v = 0.f;
            if ((unsigned)hy < 64u && (unsigned)wx < 64u)
                v = X[(size_t)c * 4096 + hy * 64 + wx];
            smem[c * 204 + r * 68 + col] = v;
        }
        __syncthreads();

        const float* Wq = WT + (size_t)kq * 9216 + oh * 8;
        float acc[8];
        #pragma unroll
        for (int t = 0; t < 8; ++t) acc[t] = 0.f;

        for (int c = 0; c < 32; ++c) {
            const float* xr = smem + c * 204 + w;
            float xv[9];
            #pragma unroll
            for (int i = 0; i < 3; ++i)
                #pragma unroll
                for (int j = 0; j < 3; ++j)
                    xv[i * 3 + j] = xr[i * 68 + j];
            #pragma unroll
            for (int ij = 0; ij < 9; ++ij) {
                const float4* wp = (const float4*)(Wq + (c * 9 + ij) * 32);
                float4 w0 = wp[0], w1 = wp[1];
                float xs = xv[ij];
                acc[0] = fmaf(xs, w0.x, acc[0]); acc[1] = fmaf(xs, w0.y, acc[1]);
                acc[2] = fmaf(xs, w0.z, acc[2]); acc[3] = fmaf(xs, w0.w, acc[3]);
                acc[4] = fmaf(xs, w1.x, acc[4]); acc[5] = fmaf(xs, w1.y, acc[5]);
                acc[6] = fmaf(xs, w1.z, acc[6]); acc[7] = fmaf(xs, w1.w, acc[7]);
            }
        }

        int pix = h * 64 + w;
        float* pp = part + (((size_t)kq * 4 + img) * 32 + oh * 8) * 4096 + pix;
        #pragma unroll
        for (int t = 0; t < 8; ++t)
            pp[(size_t)t * 4096] = acc[t];
    } else {
        // ---------------- chlast branches ----------------
        float (*tile)[33] = (float(*)[33])smem;
        int tx = tid & 31, ty = tid >> 5;   // (32, 8)
        const float* Xn; float* Xtn;
        int s0, c0, C, S;
        if (bid < 2048) {            // KV04x -> Xt4  [C=128,S=4096]
            int b = bid - 1024;
            C = 128; S = 4096;
            s0 = (b & 127) * 32; c0 = ((b >> 7) & 3) * 32;
            int n = b >> 9;
            Xn = KV0 + (size_t)n * C * S;  Xtn = Xt4 + (size_t)n * S * C;
        } else if (bid < 4096) {     // V02x -> Xt2  [C=64,S=16384]
            int b = bid - 2048;
            C = 64; S = 16384;
            s0 = (b & 511) * 32; c0 = ((b >> 9) & 1) * 32;
            int n = b >> 10;
            Xn = V02 + (size_t)n * C * S;  Xtn = Xt2 + (size_t)n * S * C;
        } else {                     // V01x -> Xt1  [C=32,S=65536]
            int b = bid - 4096;
            C = 32; S = 65536;
            s0 = (b & 2047) * 32; c0 = 0;
            int n = b >> 11;
            Xn = V01 + (size_t)n * C * S;  Xtn = Xt1 + (size_t)n * S * C;
        }
        #pragma unroll
        for (int r = 0; r < 32; r += 8)
            tile[ty + r][tx] = Xn[(size_t)(c0 + ty + r) * S + s0 + tx];
        __syncthreads();
        #pragma unroll
        for (int r = 0; r < 32; r += 8)
            Xtn[(size_t)(s0 + ty + r) * C + c0 + tx] = tile[tx][ty + r];
    }
}

// ---------------------------------------------------------------------------
// Kernel 1b: sum 4 k-partials + l2norm -> AB[(img*4096+pix)*32+o]
__global__ __launch_bounds__(512)
void reduce_norm_kernel(const float* __restrict__ part, float* __restrict__ AB) {
    int tid = threadIdx.x;
    int o4 = tid & 7;
    int w  = tid >> 3;
    int img = blockIdx.x >> 6;
    int h   = blockIdx.x & 63;
    int pix = h * 64 + w;

    float a0 = 0.f, a1 = 0.f, a2 = 0.f, a3 = 0.f;
    #pragma unroll
    for (int kq = 0; kq < 4; ++kq) {
        const float* pp = part + (((size_t)kq * 4 + img) * 32 + o4 * 4) * 4096 + pix;
        a0 += pp[0];
        a1 += pp[4096];
        a2 += pp[2 * 4096];
        a3 += pp[3 * 4096];
    }
    float ss = a0 * a0 + a1 * a1 + a2 * a2 + a3 * a3;
    ss += __shfl_xor(ss, 1, 8);
    ss += __shfl_xor(ss, 2, 8);
    ss += __shfl_xor(ss, 4, 8);
    float inv = 1.f / fmaxf(sqrtf(ss), 1e-12f);
    float4 outv = make_float4(a0 * inv, a1 * inv, a2 * inv, a3 * inv);
    *((float4*)(AB + ((size_t)img * 4096 + pix) * 32) + o4) = outv;
}

// ---------------------------------------------------------------------------
// Legacy conv (tiny-ws fallback only).
#define CB 16
__global__ __launch_bounds__(512, 2)
void conv_l2_kernel(const float* __restrict__ KVt,
                    const float* __restrict__ KV0,
                    const float* __restrict__ WT,
                    float* __restrict__ AB) {
    __shared__ float Xh[CB * 3 * 66];
    __shared__ float Wl[CB * 9 * 32];
    int tid = threadIdx.x;
    int o4 = tid & 7;
    int w  = tid >> 3;
    int img = blockIdx.x >> 6;
    int h   = blockIdx.x & 63;
    const float* X = (img < 2) ? (KVt + (size_t)img * 128 * 4096)
                               : (KV0 + (size_t)(img - 2) * 128 * 4096);
    float acc0 = 0.f, acc1 = 0.f, acc2 = 0.f, acc3 = 0.f;
    for (int cc = 0; cc < 128 / CB; ++cc) {
        __syncthreads();
        for (int t = tid; t < CB * 3 * 66; t += 512) {
            int c2 = t / 198;
            int rem = t - c2 * 198;
            int r = rem / 66, col = rem - r * 66;
            int hy = h + r - 1, wx = col - 1;
            float v = 0.f;
            if ((unsigned)hy < 64u && (unsigned)wx < 64u)
                v = X[(size_t)(cc * CB + c2) * 4096 + hy * 64 + wx];
            Xh[t] = v;
        }
        for (int t = tid; t < CB * 9 * 32; t += 512)
            Wl[t] = WT[cc * (CB * 9 * 32) + t];
        __syncthreads();
        #pragma unroll 4
        for (int c2 = 0; c2 < CB; ++c2) {
            const float* xr = Xh + c2 * 198 + w;
            float xv[9];
            #pragma unroll
            for (int i = 0; i < 3; ++i)
                #pragma unroll
                for (int j = 0; j < 3; ++j)
                    xv[i * 3 + j] = xr[i * 66 + j];
            const float4* wp = (const float4*)(Wl + c2 * 9 * 32) + o4;
            #pragma unroll
            for (int ij = 0; ij < 9; ++ij) {
                float4 wv = wp[ij * 8];
                acc0 = fmaf(xv[ij], wv.x, acc0);
                acc1 = fmaf(xv[ij], wv.y, acc1);
                acc2 = fmaf(xv[ij], wv.z, acc2);
                acc3 = fmaf(xv[ij], wv.w, acc3);
            }
        }
    }
    float ss = acc0 * acc0 + acc1 * acc1 + acc2 * acc2 + acc3 * acc3;
    ss += __shfl_xor(ss, 1, 8);
    ss += __shfl_xor(ss, 2, 8);
    ss += __shfl_xor(ss, 4, 8);
    float inv = 1.f / fmaxf(sqrtf(ss), 1e-12f);
    int pix = h * 64 + w;
    float4 outv = make_float4(acc0 * inv, acc1 * inv, acc2 * inv, acc3 * inv);
    *((float4*)(AB + ((size_t)img * 4096 + pix) * 32) + o4) = outv;
}

// ---------------------------------------------------------------------------
// Kernel 2 v3: 2 adjacent pixels per wave share the B window (17x18 union,
// 306 loads instead of 2x289 = 47% traffic cut). lane = dg*8+q as before.
// Per cell e: one b-load feeds both pixels' dots; d1 = d0 - 1 with edge guards.
__global__ __launch_bounds__(256)
void corr_flow_kernel(const float* __restrict__ A,
                      const float* __restrict__ B,
                      const float* __restrict__ subW,
                      float* __restrict__ maxOut,
                      float4* __restrict__ recs) {
    __shared__ float cosb[4][2][306];

    int tid = threadIdx.x;
    int wslot = tid >> 6;
    int lane = tid & 63;
    int q  = lane & 7;
    int dg = lane >> 3;
    int v = (blockIdx.x * 256 + tid) >> 6;   // wave id 0..4095 (2 px each)
    int n = v >> 11;
    int pp = v & 2047;
    int h = pp >> 5;
    int w0 = (pp & 31) * 2;
    int pix0 = h * 64 + w0;

    float4 a0 = *((const float4*)(A + ((size_t)n * 4096 + pix0) * 32) + q);
    float4 a1 = *((const float4*)(A + ((size_t)n * 4096 + pix0 + 1) * 32) + q);
    const float* Bn = B + (size_t)n * 4096 * 32;

    float bV0 = -INFINITY, bV1 = -INFINITY;
    int bD0 = 0x7fffffff, bD1 = 0x7fffffff;

    #pragma unroll 4
    for (int it = 0; it < 39; ++it) {
        int e = it * 8 + dg;                 // cell in 17x18 union window
        if (e < 306) {
            int dv  = e / 18 - 8;
            int duu = e % 18 - 8;            // in [-8, 9], relative to w0
            int hy = h + dv, wx = w0 + duu;
            float c0 = 0.f, c1 = 0.f;
            if ((unsigned)hy < 64u && (unsigned)wx < 64u) {
                float4 bv = *((const float4*)(Bn + ((size_t)hy * 64 + wx) * 32) + q);
                c0 = a0.x * bv.x + a0.y * bv.y + a0.z * bv.z + a0.w * bv.w;
                c1 = a1.x * bv.x + a1.y * bv.y + a1.z * bv.z + a1.w * bv.w;
            }
            c0 += __shfl_xor(c0, 1, 8); c0 += __shfl_xor(c0, 2, 8); c0 += __shfl_xor(c0, 4, 8);
            c1 += __shfl_xor(c1, 1, 8); c1 += __shfl_xor(c1, 2, 8); c1 += __shfl_xor(c1, 4, 8);
            int d0 = (dv + 8) * 17 + (duu + 8);
            int d1 = d0 - 1;
            if (duu <= 8) {                  // valid bin for pixel0 (du0 = duu)
                if (q == 0) cosb[wslot][0][d0] = c0;
                if (c0 > bV0) { bV0 = c0; bD0 = d0; }   // d ascending per lane
            }
            if (duu >= -7) {                 // valid bin for pixel1 (du1 = duu-1)
                if (q == 0) cosb[wslot][1][d1] = c1;
                if (c1 > bV1) { bV1 = c1; bD1 = d1; }
            }
        }
    }
    // butterflies: larger value wins; exact tie -> smaller d (first occurrence)
    #pragma unroll
    for (int m = 1; m < 64; m <<= 1) {
        float ov0 = __shfl_xor(bV0, m, 64); int od0 = __shfl_xor(bD0, m, 64);
        if (ov0 > bV0 || (ov0 == bV0 && od0 < bD0)) { bV0 = ov0; bD0 = od0; }
        float ov1 = __shfl_xor(bV1, m, 64); int od1 = __shfl_xor(bD1, m, 64);
        if (ov1 > bV1 || (ov1 == bV1 && od1 < bD1)) { bV1 = ov1; bD1 = od1; }
    }
    __syncthreads();

    if (lane < 2) {
        float bestV = lane ? bV1 : bV0;
        int bestD   = lane ? bD1 : bD0;
        const float* cb = cosb[wslot][lane];
        int wsel = w0 + lane;
        int mi = bestD / 17, mj = bestD % 17;
        float hard[4] = {0.f, 0.f, 0.f, 0.f};
        #pragma unroll
        for (int p = 0; p < 3; ++p) {
            #pragma unroll
            for (int q3 = 0; q3 < 3; ++q3) {
                int ii = mi - 1 + p, jj = mj - 1 + q3;
                float l2v = 2.f;
                if ((unsigned)ii < 17u && (unsigned)jj < 17u)
                    l2v = 2.f - 2.f * cb[ii * 17 + jj];
                #pragma unroll
                for (int o = 0; o < 4; ++o)
                    hard[o] = fmaf(subW[o * 9 + p * 3 + q3], l2v, hard[o]);
            }
        }
        float subU = fminf(fmaxf(-hard[2] / fmaxf(hard[0], 1e-6f), -1.f), 1.f);
        float subV = fminf(fmaxf(-hard[3] / fmaxf(hard[1], 1e-6f), -1.f), 1.f);
        float u = (float)(mj - 8) + subU;
        float vv = (float)(mi - 8) + subV;
        maxOut[(size_t)n * 4096 + pix0 + lane] = bestV;
        float xf = (float)wsel + u, yf = (float)h + vv;
        float x0 = floorf(xf), y0 = floorf(yf);
        recs[(size_t)n * 4096 + pix0 + lane] = make_float4(x0, y0, xf - x0, yf - y0);
    }
}

// ---------------------------------------------------------------------------
// foldwarp body: 3-tap batched gathers.
template <int ST, int PAD, int HIN, int C>
__device__ __forceinline__
void foldwarp_body(int b, int tid, const float* __restrict__ Xt,
                   const float4* __restrict__ recs, float* __restrict__ out,
                   char* smem) {
    constexpr int HOUT = 64 * ST;
    constexpr int NC4 = C / 4;
    constexpr int XT = 256 / NC4;
    constexpr int XB = HOUT / XT;

    int4*   tO = (int4*)smem;                       // XT*9
    float4* tW = (float4*)(smem + XT * 9 * 16);     // XT*9
    float*  ob = (float*)(smem + XT * 9 * 32);      // XT*(C+1)

    int xblk = b % XB;
    int rest = b / XB;
    int y = rest % HOUT;
    int n = rest / HOUT;
    int c4 = tid % NC4;
    int lx = tid / NC4;

    int ry = (y + PAD) % ST;
    for (int e = tid; e < XT * 9; e += 256) {
        int ex = e / 9, tap = e - ex * 9;
        int ti = tap / 3, tj = tap - ti * 3;
        int xx = xblk * XT + ex;
        int i = ry + ti * ST;
        int ho = (y + PAD - i) / ST;
        int rxx = (xx + PAD) % ST;
        int j = rxx + tj * ST;
        int wo = (xx + PAD - j) / ST;
        int4 off = make_int4(0, 0, 0, 0);
        float4 wt = make_float4(0.f, 0.f, 0.f, 0.f);
        if ((unsigned)ho < 64u && (unsigned)wo < 64u) {
            float4 r = recs[n * 4096 + ho * 64 + wo];
            int x0 = (int)r.x, y0 = (int)r.y;
            float fx = r.z, fy = r.w;
            int offs[4]; float ws[4];
            #pragma unroll
            for (int k = 0; k < 4; ++k) {
                int dy = k >> 1, dx = k & 1;
                int yc = y0 + dy, xc = x0 + dx;
                int iy = i + yc * ST - PAD;
                int ix = j + xc * ST - PAD;
                bool v = ((unsigned)yc < 64u) && ((unsigned)xc < 64u) &&
                         ((unsigned)iy < (unsigned)HIN) && ((unsigned)ix < (unsigned)HIN);
                ws[k]   = v ? (dy ? r.w : 1.f - fy) * (dx ? fx : 1.f - fx) : 0.f;
                offs[k] = v ? (iy * HIN + ix) * C : 0;
            }
            off = make_int4(offs[0], offs[1], offs[2], offs[3]);
            wt  = make_float4(ws[0], ws[1], ws[2], ws[3]);
        }
        tO[e] = off;
        tW[e] = wt;
    }
    __syncthreads();

    const float* Xn = Xt + (size_t)n * HIN * HIN * C + c4 * 4;
    float a0 = 0.f, a1 = 0.f, a2 = 0.f, a3 = 0.f;
    #pragma unroll
    for (int g = 0; g < 3; ++g) {
        int4 o0 = tO[lx * 9 + g * 3 + 0];
        int4 o1 = tO[lx * 9 + g * 3 + 1];
        int4 o2 = tO[lx * 9 + g * 3 + 2];
        float4 v00 = *(const float4*)(Xn + o0.x);
        float4 v01 = *(const float4*)(Xn + o0.y);
        float4 v02 = *(const float4*)(Xn + o0.z);
        float4 v03 = *(const float4*)(Xn + o0.w);
        float4 v10 = *(const float4*)(Xn + o1.x);
        float4 v11 = *(const float4*)(Xn + o1.y);
        float4 v12 = *(const float4*)(Xn + o1.z);
        float4 v13 = *(const float4*)(Xn + o1.w);
        float4 v20 = *(const float4*)(Xn + o2.x);
        float4 v21 = *(const float4*)(Xn + o2.y);
        float4 v22 = *(const float4*)(Xn + o2.z);
        float4 v23 = *(const float4*)(Xn + o2.w);
        float4 w0 = tW[lx * 9 + g * 3 + 0];
        float4 w1 = tW[lx * 9 + g * 3 + 1];
        float4 w2 = tW[lx * 9 + g * 3 + 2];
        a0 = fmaf(w0.x, v00.x, a0); a1 = fmaf(w0.x, v00.y, a1);
        a2 = fmaf(w0.x, v00.z, a2); a3 = fmaf(w0.x, v00.w, a3);
        a0 = fmaf(w0.y, v01.x, a0); a1 = fmaf(w0.y, v01.y, a1);
        a2 = fmaf(w0.y, v01.z, a2); a3 = fmaf(w0.y, v01.w, a3);
        a0 = fmaf(w0.z, v02.x, a0); a1 = fmaf(w0.z, v02.y, a1);
        a2 = fmaf(w0.z, v02.z, a2); a3 = fmaf(w0.z, v02.w, a3);
        a0 = fmaf(w0.w, v03.x, a0); a1 = fmaf(w0.w, v03.y, a1);
        a2 = fmaf(w0.w, v03.z, a2); a3 = fmaf(w0.w, v03.w, a3);
        a0 = fmaf(w1.x, v10.x, a0); a1 = fmaf(w1.x, v10.y, a1);
        a2 = fmaf(w1.x, v10.z, a2); a3 = fmaf(w1.x, v10.w, a3);
        a0 = fmaf(w1.y, v11.x, a0); a1 = fmaf(w1.y, v11.y, a1);
        a2 = fmaf(w1.y, v11.z, a2); a3 = fmaf(w1.y, v11.w, a3);
        a0 = fmaf(w1.z, v12.x, a0); a1 = fmaf(w1.z, v12.y, a1);
        a2 = fmaf(w1.z, v12.z, a2); a3 = fmaf(w1.z, v12.w, a3);
        a0 = fmaf(w1.w, v13.x, a0); a1 = fmaf(w1.w, v13.y, a1);
        a2 = fmaf(w1.w, v13.z, a2); a3 = fmaf(w1.w, v13.w, a3);
        a0 = fmaf(w2.x, v20.x, a0); a1 = fmaf(w2.x, v20.y, a1);
        a2 = fmaf(w2.x, v20.z, a2); a3 = fmaf(w2.x, v20.w, a3);
        a0 = fmaf(w2.y, v21.x, a0); a1 = fmaf(w2.y, v21.y, a1);
        a2 = fmaf(w2.y, v21.z, a2); a3 = fmaf(w2.y, v21.w, a3);
        a0 = fmaf(w2.z, v22.x, a0); a1 = fmaf(w2.z, v22.y, a1);
        a2 = fmaf(w2.z, v22.z, a2); a3 = fmaf(w2.z, v22.w, a3);
        a0 = fmaf(w2.w, v23.x, a0); a1 = fmaf(w2.w, v23.y, a1);
        a2 = fmaf(w2.w, v23.z, a2); a3 = fmaf(w2.w, v23.w, a3);
    }
    const float s9 = 1.f / 9.f;
    ob[lx * (C + 1) + c4 * 4 + 0] = a0 * s9;
    ob[lx * (C + 1) + c4 * 4 + 1] = a1 * s9;
    ob[lx * (C + 1) + c4 * 4 + 2] = a2 * s9;
    ob[lx * (C + 1) + c4 * 4 + 3] = a3 * s9;
    __syncthreads();

    float* on = out + ((size_t)n * C * HOUT + y) * HOUT + xblk * XT;
    for (int e = tid; e < XT * C; e += 256) {
        int c = e / XT, xx = e - c * XT;
        on[(size_t)c * HOUT * HOUT + xx] = ob[xx * (C + 1) + c];
    }
}

// foldwarp_all with XCD banding: xcd = bid&7 (HW round-robins blocks to XCDs),
// slot = bid>>3. Per XCD: contiguous bands -> private L2 stays hot.
__global__ __launch_bounds__(256)
void foldwarp_all_kernel(const float* __restrict__ Xt4, const float* __restrict__ Xt2,
                         const float* __restrict__ Xt1, const float4* __restrict__ recs,
                         float* __restrict__ T4, float* __restrict__ T2,
                         float* __restrict__ T1) {
    __shared__ alignas(16) char smem[13440];
    int bid = blockIdx.x, tid = threadIdx.x;
    int xcd  = bid & 7;
    int slot = bid >> 3;          // 0..895 per XCD
    if (slot < 512)
        foldwarp_body<4, 4, 256, 32>(xcd * 512 + slot, tid, Xt1, recs, T1, smem);
    else if (slot < 640)
        foldwarp_body<1, 1, 64, 128>(xcd * 128 + (slot - 512), tid, Xt4, recs, T4, smem);
    else
        foldwarp_body<2, 2, 128, 64>(xcd * 256 + (slot - 640), tid, Xt2, recs, T2, smem);
}

// ---------------------------------------------------------------------------
// Kernel 3 v1 (fallback when ws is too small for transposed buffers).
template <int ST, int PAD, int HIN, int C>
__global__ void foldwarp_kernel(const float* __restrict__ X,
                                const float4* __restrict__ recs,
                                float* __restrict__ out) {
    constexpr int HOUT = 64 * ST;
    int t = blockIdx.x * 256 + threadIdx.x;
    int x = t % HOUT;
    int rest = t / HOUT;
    int y = rest % HOUT; rest /= HOUT;
    int c = rest % C;
    int n = rest / C;

    int ry = (y + PAD) % ST;
    int rx = (x + PAD) % ST;
    float acc = 0.f;
    #pragma unroll
    for (int ti = 0; ti < 3; ++ti) {
        int i = ry + ti * ST;
        int ho = (y + PAD - i) / ST;
        if ((unsigned)ho >= 64u) continue;
        #pragma unroll
        for (int tj = 0; tj < 3; ++tj) {
            int j = rx + tj * ST;
            int wo = (x + PAD - j) / ST;
            if ((unsigned)wo >= 64u) continue;
            float4 r = recs[n * 4096 + ho * 64 + wo];
            int x0 = (int)r.x, y0 = (int)r.y;
            float fx = r.z, fy = r.w;
            #pragma unroll
            for (int dy = 0; dy < 2; ++dy) {
                int yc = y0 + dy;
                if ((unsigned)yc >= 64u) continue;
                int iy = i + yc * ST - PAD;
                if ((unsigned)iy >= (unsigned)HIN) continue;
                float wgy = dy ? fy : (1.f - fy);
                #pragma unroll
                for (int dx = 0; dx < 2; ++dx) {
                    int xc = x0 + dx;
                    if ((unsigned)xc >= 64u) continue;
                    int ix = j + xc * ST - PAD;
                    if ((unsigned)ix >= (unsigned)HIN) continue;
                    float wgt = wgy * (dx ? fx : (1.f - fx));
                    acc = fmaf(X[(((size_t)n * C + c) * HIN + iy) * HIN + ix], wgt, acc);
                }
            }
        }
    }
    out[t] = acc * (1.f / 9.f);
}

// ---------------------------------------------------------------------------
extern "C" void kernel_launch(void* const* d_in, const int* in_sizes, int n_in,
                              void* d_out, int out_size, void* d_ws, size_t ws_size,
                              hipStream_t stream) {
    const float* KVt4x = (const float*)d_in[2];
    const float* V01x  = (const float*)d_in[3];
    const float* V02x  = (const float*)d_in[4];
    const float* KV04x = (const float*)d_in[5];
    const float* subA  = (const float*)d_in[6];
    const float* W_in  = (const float*)d_in[7];

    float* out = (float*)d_out;
    float* maxOut = out;
    float* T4 = out + 8192;
    float* T2 = T4 + 2 * 128 * 64 * 64;
    float* T1 = T2 + 2 * 64 * 128 * 128;

    float* ws = (float*)d_ws;
    float* WT = ws;                        // 36864
    float* AB = WT + 36864;                // 524288 (A = imgs 0-1, B = imgs 2-3)
    float* A  = AB;
    float* B  = AB + 262144;
    float4* recs = (float4*)(AB + 524288); // 8192 float4 = 32768 floats
    float* Xt4 = (float*)(recs + 8192);    // 2*4096*128  = 1048576
    float* Xt2 = Xt4 + 1048576;            // 2*16384*64  = 2097152
    float* Xt1 = Xt2 + 2097152;            // 2*65536*32  = 4194304
    float* part = Xt1 + 4194304;           // 4kq*4img*32*4096 = 2097152

    const size_t need_full = (36864ull + 524288 + 32768 +
                              1048576 + 2097152 + 4194304 + 2097152) * 4ull;
    const size_t need_min  = (36864ull + 524288 + 32768) * 4ull;

    hipLaunchKernelGGL(wtrans_kernel, dim3(144), dim3(256), 0, stream, W_in, WT);

    if (ws_size >= need_full) {
        hipLaunchKernelGGL(combo1_kernel, dim3(8192), dim3(256), 0, stream,
                           KVt4x, KV04x, V01x, V02x, WT, part, Xt4, Xt2, Xt1);
        hipLaunchKernelGGL(reduce_norm_kernel, dim3(256), dim3(512), 0, stream,
                           part, AB);
        hipLaunchKernelGGL(corr_flow_kernel, dim3(1024), dim3(256), 0, stream,
                           A, B, subA, maxOut, recs);
        hipLaunchKernelGGL(foldwarp_all_kernel, dim3(7168), dim3(256), 0, stream,
                           Xt4, Xt2, Xt1, recs, T4, T2, T1);
    } else if (ws_size >= need_min) {
        hipLaunchKernelGGL(conv_l2_kernel, dim3(256), dim3(512), 0, stream,
                           KVt4x, KV04x, WT, AB);
        hipLaunchKernelGGL(corr_flow_kernel, dim3(1024), dim3(256), 0, stream,
                           A, B, subA, maxOut, recs);
        hipLaunchKernelGGL((foldwarp_kernel<1, 1, 64, 128>),  dim3(4096),  dim3(256), 0, stream, KV04x, recs, T4);
        hipLaunchKernelGGL((foldwarp_kernel<2, 2, 128, 64>),  dim3(8192),  dim3(256), 0, stream, V02x, recs, T2);
        hipLaunchKernelGGL((foldwarp_kernel<4, 4, 256, 32>),  dim3(16384), dim3(256), 0, stream, V01x, recs, T1);
    }
}